// Round 11
// baseline (978.629 us; speedup 1.0000x reference)
//
#include <hip/hip_runtime.h>
#include <cstdint>

typedef unsigned short u16;

#define AVG_LOG_F 1.4862356961977451f
#define MAXD 64

// ---- workspace float-unit offsets (weights region) ----
#define OFF_W1   0      // pre_w1  fp32 [4][48][16] (row-major, used for eWtab)
#define OFF_W2   3072   // pre_w2  fp32 [4][16][16]
#define OFF_PW1  4096   // post_w1 fp32 TRANSPOSED [4][16 g][256 r]
#define OFF_PW2  20480  // post_w2 fp32 [4][16][16]
#define OFF_LW   21504  // lin_w   fp32 TRANSPOSED [64 l][64 f]
#define OFF_PB1  25600
#define OFF_PB2  25664
#define OFF_QB1  25728
#define OFF_QB2  25792
#define OFF_LB   25856
#define OFF_LG   25920
#define OFF_LBN  25984
#define OFF_ET   26048  // e_table fp32 [5][16]
#define OFF_EWT  26128  // eWtab  fp32 [5][64]  (pb1 + ET.W1e, node-invariant)
#define IB       26448  // int region start (4B units)

__device__ __forceinline__ float bf2f(u16 u) {
    return __uint_as_float(((unsigned)u) << 16);
}
__device__ __forceinline__ u16 f2bf(float f) {
    unsigned u = __float_as_uint(f);
    u += 0x7fffu + ((u >> 16) & 1u);
    return (u16)(u >> 16);
}
__device__ __forceinline__ float rdin(const void* p, long j, int mode) {
    if (mode == 0) return bf2f(((const u16*)p)[j]);
    return ((const float*)p)[j];
}
template <int MODE>
__device__ __forceinline__ void load16c(const void* p, long base, float* o) {
    if (MODE == 0) {
        const u16* q = (const u16*)p + base;
        uint4 a = *(const uint4*)q;
        uint4 b = *(const uint4*)(q + 8);
        o[0]  = __uint_as_float(a.x << 16); o[1]  = __uint_as_float(a.x & 0xffff0000u);
        o[2]  = __uint_as_float(a.y << 16); o[3]  = __uint_as_float(a.y & 0xffff0000u);
        o[4]  = __uint_as_float(a.z << 16); o[5]  = __uint_as_float(a.z & 0xffff0000u);
        o[6]  = __uint_as_float(a.w << 16); o[7]  = __uint_as_float(a.w & 0xffff0000u);
        o[8]  = __uint_as_float(b.x << 16); o[9]  = __uint_as_float(b.x & 0xffff0000u);
        o[10] = __uint_as_float(b.y << 16); o[11] = __uint_as_float(b.y & 0xffff0000u);
        o[12] = __uint_as_float(b.z << 16); o[13] = __uint_as_float(b.z & 0xffff0000u);
        o[14] = __uint_as_float(b.w << 16); o[15] = __uint_as_float(b.w & 0xffff0000u);
    } else {
        const float* q = (const float*)p + base;
        float4 a = *(const float4*)q;
        float4 b = *(const float4*)(q + 4);
        float4 c = *(const float4*)(q + 8);
        float4 d = *(const float4*)(q + 12);
        o[0]=a.x; o[1]=a.y; o[2]=a.z; o[3]=a.w;
        o[4]=b.x; o[5]=b.y; o[6]=b.z; o[7]=b.w;
        o[8]=c.x; o[9]=c.y; o[10]=c.z; o[11]=c.w;
        o[12]=d.x; o[13]=d.y; o[14]=d.z; o[15]=d.w;
    }
}

// per-node precompute: Y = x.W1_xj col, XW = x.W1_xi col, XP = x.PW1_x col
template <int MODE>
__device__ __forceinline__ void y_loop(const void* ax, const void* pre_w1, const void* post_w1,
                                       float* wsY, float* wsXW, float* wsXP,
                                       int Nn, int wave, int nwaves, int l) {
    const int t = l >> 4, g = l & 15;
    float wxi[16], wxj[16], wxp[16];
#pragma unroll
    for (int f = 0; f < 16; f++) {
        wxi[f] = rdin(pre_w1,  t * 768  + f * 16 + g, MODE);
        wxj[f] = rdin(pre_w1,  t * 768  + (16 + f) * 16 + g, MODE);
        wxp[f] = rdin(post_w1, t * 4096 + f * 16 + g, MODE);
    }
    for (int n = wave; n < Nn; n += nwaves) {
        float xj[16];
        load16c<MODE>(ax, (long)n * 64 + t * 16, xj);
        float accY = 0.f, accX = 0.f, accP = 0.f;
#pragma unroll
        for (int f = 0; f < 16; f++) {
            accY = fmaf(xj[f], wxj[f], accY);
            accX = fmaf(xj[f], wxi[f], accX);
            accP = fmaf(xj[f], wxp[f], accP);
        }
        wsY[(long)n * 64 + l]  = accY;
        wsXW[(long)n * 64 + l] = accX;
        wsXP[(long)n * 64 + l] = accP;
    }
}

// ---------------- 1: init: dtype, zero cnt, weights -> fp32 (PW1/LW transposed), Y/XW/XP ----
__global__ __launch_bounds__(256) void k_init(
    const void* bond_emb, const void* edge_w, const void* edge_b,
    const void* pre_w1, const void* pre_b1, const void* pre_w2, const void* pre_b2,
    const void* post_w1, const void* post_b1, const void* post_w2, const void* post_b2,
    const void* lin_w, const void* lin_b, const void* ln_g, const void* ln_b,
    const void* ax, float* wsf, float* wsY, float* wsXW, float* wsXP,
    int* cnt, int* modep, int Nn)
{
    __shared__ int csh;
    int tid = threadIdx.x;
    if (tid == 0) csh = 0;
    __syncthreads();
    {
        unsigned v = ((const unsigned*)ax)[tid];
        unsigned lo = v & 0xffffu;
        int e = (int)((lo >> 7) & 0xff);
        int isbf = (lo == 0u) || (e >= 110 && e <= 140);
        atomicAdd(&csh, isbf);
    }
    __syncthreads();
    int mode = (csh >= 192) ? 0 : 1;

    int gt = blockIdx.x * 256 + tid;
    int gs = gridDim.x * 256;
    if (gt < Nn) cnt[gt] = 0;
    if (blockIdx.x == 0 && tid == 0) modep[0] = mode;

    for (int j = gt; j < 3072; j += gs)  wsf[OFF_W1 + j]  = rdin(pre_w1, j, mode);
    for (int j = gt; j < 1024; j += gs)  wsf[OFF_W2 + j]  = rdin(pre_w2, j, mode);
    // post_w1 transposed: dst j = t*4096 + g*256 + r ; src = t*4096 + r*16 + g
    for (int j = gt; j < 16384; j += gs) {
        int tt = j >> 12, gg = (j >> 8) & 15, rr = j & 255;
        wsf[OFF_PW1 + j] = rdin(post_w1, tt * 4096 + rr * 16 + gg, mode);
    }
    for (int j = gt; j < 1024; j += gs)  wsf[OFF_PW2 + j] = rdin(post_w2, j, mode);
    // lin_w transposed: dst j = l*64 + f ; src = f*64 + l
    for (int j = gt; j < 4096; j += gs)
        wsf[OFF_LW + j] = rdin(lin_w, (long)(j & 63) * 64 + (j >> 6), mode);
    for (int j = gt; j < 64; j += gs) {
        wsf[OFF_PB1 + j] = rdin(pre_b1, j, mode);
        wsf[OFF_PB2 + j] = rdin(pre_b2, j, mode);
        wsf[OFF_QB1 + j] = rdin(post_b1, j, mode);
        wsf[OFF_QB2 + j] = rdin(post_b2, j, mode);
        wsf[OFF_LB + j]  = rdin(lin_b, j, mode);
        wsf[OFF_LG + j]  = rdin(ln_g, j, mode);
        wsf[OFF_LBN + j] = rdin(ln_b, j, mode);
    }
    if (gt < 80) {
        int b = gt >> 4, f = gt & 15;
        float acc = rdin(edge_b, f, mode);
        for (int k = 0; k < 64; k++)
            acc = fmaf(rdin(bond_emb, b * 64 + k, mode), rdin(edge_w, k * 16 + f, mode), acc);
        wsf[OFF_ET + gt] = acc;
    }
    int wave = gt >> 6;
    int nwaves = gs >> 6;
    int l = tid & 63;
    if (mode == 0) y_loop<0>(ax, pre_w1, post_w1, wsY, wsXW, wsXP, Nn, wave, nwaves, l);
    else           y_loop<1>(ax, pre_w1, post_w1, wsY, wsXW, wsXP, Nn, wave, nwaves, l);
}

// ---------------- 2: count+scatter into fixed-stride buckets; block 0 also builds eWtab ----
__global__ __launch_bounds__(256) void k_scatter(
    const int* __restrict__ dstp, const int* __restrict__ srcp, const int* __restrict__ bondp,
    int* __restrict__ cnt, int* __restrict__ pk, float* __restrict__ wsf, int E)
{
    if (blockIdx.x == 0) {
        for (int j = threadIdx.x; j < 320; j += 256) {
            int b = j >> 6, ll = j & 63, tt = ll >> 4, gg = ll & 15;
            float acc = wsf[OFF_PB1 + tt * 16 + gg];
#pragma unroll
            for (int f = 0; f < 16; f++)
                acc = fmaf(wsf[OFF_ET + b * 16 + f], wsf[OFF_W1 + tt * 768 + (32 + f) * 16 + gg], acc);
            wsf[OFF_EWT + j] = acc;
        }
    }
    int e = blockIdx.x * 256 + threadIdx.x;
    if (e < E) {
        int d = dstp[e];
        int pos = atomicAdd(&cnt[d], 1);
        if (pos < MAXD) pk[d * MAXD + pos] = (srcp[e] << 3) | (bondp[e] & 7);
    }
}

// ---------------- 3: persistent wave-per-node fully-fused kernel ----------------
__global__ __launch_bounds__(256, 4) void k_node(
    const void* __restrict__ ax, const float* __restrict__ Yp, const float* __restrict__ XWp,
    const float* __restrict__ XPp, const int* __restrict__ pk, const int* __restrict__ cnt,
    const float* __restrict__ wsf, void* __restrict__ outp,
    const int* __restrict__ modep, int Nn, int nwaves)
{
    __shared__ float hb[4][8][64];
    const int w = threadIdx.x >> 6;
    const int l = threadIdx.x & 63;
    const int t = l >> 4;
    const int g = l & 15;
    const int mode = modep[0];
    const int wid = blockIdx.x * 4 + w;

    // ---- wave-lifetime constants (amortized over ~Nn/nwaves nodes) ----
    const float* W2  = wsf + OFF_W2  + t * 256;
    const float* PW2 = wsf + OFF_PW2 + t * 256;
    const float* PT  = wsf + OFF_PW1 + t * 4096 + g * 256;   // transposed PW1, this lane's column
    const float* LT  = wsf + OFF_LW + l * 64;                // transposed lin_w, this lane's column

    float w2c[16], pw2c[16];
#pragma unroll
    for (int f = 0; f < 16; f++) {
        w2c[f]  = W2[f * 16 + g];
        pw2c[f] = PW2[f * 16 + g];
    }
    float pb2g = wsf[OFF_PB2 + t * 16 + g];
    float qb1g = wsf[OFF_QB1 + t * 16 + g];
    float qb2g = wsf[OFF_QB2 + t * 16 + g];
    float eW0 = wsf[OFF_EWT + 0 * 64 + l];
    float eW1 = wsf[OFF_EWT + 1 * 64 + l];
    float eW2 = wsf[OFF_EWT + 2 * 64 + l];
    float eW3 = wsf[OFF_EWT + 3 * 64 + l];
    float eW4 = wsf[OFF_EWT + 4 * 64 + l];
    float lb  = wsf[OFF_LB + l];
    float lgm = wsf[OFF_LG + l];
    float lbn = wsf[OFF_LBN + l];

    for (int n = wid; n < Nn; n += nwaves) {
        int deg = cnt[n];
        if (deg > MAXD) deg = MAXD;
        int   pkvAll = pk[n * MAXD + l];
        float XWv    = XWp[(long)n * 64 + l];
        float zw0 = XWv + eW0, zw1 = XWv + eW1, zw2 = XWv + eW2;
        float zw3 = XWv + eW3, zw4 = XWv + eW4;

        float s = 0.f, s2 = 0.f, mn = 3.0e38f, mx = -3.0e38f;

        auto phaseA = [&](int srclane, int k) {
            int v = __builtin_amdgcn_readlane(pkvAll, srclane);
            float yv = Yp[((long)(v >> 3) << 6) + l];
            int bd = v & 7;
            float zt = (bd == 0) ? zw0 : (bd == 1) ? zw1 : (bd == 2) ? zw2
                     : (bd == 3) ? zw3 : zw4;
            hb[w][k][l] = fmaxf(yv + zt, 0.f);
        };
        auto phaseB = [&](int k) {
            const float4* hp = (const float4*)&hb[w][k][t * 16];
            float4 h0 = hp[0], h1 = hp[1], h2 = hp[2], h3 = hp[3];
            float m = pb2g;
            m = fmaf(h0.x, w2c[0],  m); m = fmaf(h0.y, w2c[1],  m);
            m = fmaf(h0.z, w2c[2],  m); m = fmaf(h0.w, w2c[3],  m);
            m = fmaf(h1.x, w2c[4],  m); m = fmaf(h1.y, w2c[5],  m);
            m = fmaf(h1.z, w2c[6],  m); m = fmaf(h1.w, w2c[7],  m);
            m = fmaf(h2.x, w2c[8],  m); m = fmaf(h2.y, w2c[9],  m);
            m = fmaf(h2.z, w2c[10], m); m = fmaf(h2.w, w2c[11], m);
            m = fmaf(h3.x, w2c[12], m); m = fmaf(h3.y, w2c[13], m);
            m = fmaf(h3.z, w2c[14], m); m = fmaf(h3.w, w2c[15], m);
            s += m;
            s2 = fmaf(m, m, s2);
            mn = fminf(mn, m);
            mx = fmaxf(mx, m);
        };

#pragma unroll
        for (int kb = 0; kb < MAXD; kb += 8) {
            if (kb >= deg) break;
            int B = deg - kb; if (B > 8) B = 8;
            if (B == 8) {
#pragma unroll
                for (int k = 0; k < 8; k++) phaseA(kb + k, k);
#pragma unroll
                for (int k = 0; k < 8; k++) phaseB(k);
            } else {
                for (int k = 0; k < B; k++) phaseA(kb + k, k);
                for (int k = 0; k < B; k++) phaseB(k);
            }
        }

        if (deg == 0) { mn = 0.f; mx = 0.f; }
        float cf = (float)(deg > 0 ? deg : 1);
        float inv = 1.0f / cf;
        float mean = s * inv;
        float var = s2 * inv - mean * mean;
        float sd = sqrtf(fmaxf(var, 0.f) + 1e-5f);
        float ldv = logf(cf + 1.0f);
        float sc1 = ldv * (1.0f / AVG_LOG_F);
        float sc2 = AVG_LOG_F / ldv;

        hb[w][0][l] = s;
        hb[w][1][l] = mn;
        hb[w][2][l] = mx;
        hb[w][3][l] = sd;

        float p1 = qb1g + XPp[(long)n * 64 + l];

        auto aggW = [&](const float av[16], int a) {
            int rb = 16 + a * 16;
            const float4* bp = (const float4*)(PT + rb);
            const float4* mp = (const float4*)(PT + rb + 80);
            const float4* tp = (const float4*)(PT + rb + 160);
            float4 b0 = bp[0], b1 = bp[1], b2 = bp[2], b3 = bp[3];
            float4 m0 = mp[0], m1 = mp[1], m2_ = mp[2], m3 = mp[3];
            float4 t0 = tp[0], t1 = tp[1], t2 = tp[2], t3 = tp[3];
            float bb[16] = {b0.x,b0.y,b0.z,b0.w, b1.x,b1.y,b1.z,b1.w,
                            b2.x,b2.y,b2.z,b2.w, b3.x,b3.y,b3.z,b3.w};
            float mm[16] = {m0.x,m0.y,m0.z,m0.w, m1.x,m1.y,m1.z,m1.w,
                            m2_.x,m2_.y,m2_.z,m2_.w, m3.x,m3.y,m3.z,m3.w};
            float tt[16] = {t0.x,t0.y,t0.z,t0.w, t1.x,t1.y,t1.z,t1.w,
                            t2.x,t2.y,t2.z,t2.w, t3.x,t3.y,t3.z,t3.w};
#pragma unroll
            for (int f = 0; f < 16; f++) {
                float wv = fmaf(sc2, tt[f], fmaf(sc1, mm[f], bb[f]));
                p1 = fmaf(av[f], wv, p1);
            }
        };

        float sa[16];
        {
            const float4* rp = (const float4*)&hb[w][0][t * 16];
            float4 r0 = rp[0], r1 = rp[1], r2 = rp[2], r3 = rp[3];
            float tmp[16] = {r0.x,r0.y,r0.z,r0.w, r1.x,r1.y,r1.z,r1.w,
                             r2.x,r2.y,r2.z,r2.w, r3.x,r3.y,r3.z,r3.w};
#pragma unroll
            for (int f = 0; f < 16; f++) sa[f] = tmp[f];
        }
        aggW(sa, 0);                                   // sum
        {
            float ma[16];
#pragma unroll
            for (int f = 0; f < 16; f++) ma[f] = sa[f] * inv;   // mean row, derived (bit-exact)
            aggW(ma, 1);
        }
#pragma unroll
        for (int a = 2; a < 5; a++) {                  // mn, mx, sd rows
            const float4* rp = (const float4*)&hb[w][a - 1][t * 16];
            float4 r0 = rp[0], r1 = rp[1], r2 = rp[2], r3 = rp[3];
            float av[16] = {r0.x,r0.y,r0.z,r0.w, r1.x,r1.y,r1.z,r1.w,
                            r2.x,r2.y,r2.z,r2.w, r3.x,r3.y,r3.z,r3.w};
            aggW(av, a);
        }
        p1 = fmaxf(p1, 0.f);

        hb[w][4][l] = p1;
        float m2 = qb2g;
        {
            const float4* pp = (const float4*)&hb[w][4][t * 16];
            float4 p0 = pp[0], q1 = pp[1], q2 = pp[2], q3 = pp[3];
            m2 = fmaf(p0.x, pw2c[0],  m2); m2 = fmaf(p0.y, pw2c[1],  m2);
            m2 = fmaf(p0.z, pw2c[2],  m2); m2 = fmaf(p0.w, pw2c[3],  m2);
            m2 = fmaf(q1.x, pw2c[4],  m2); m2 = fmaf(q1.y, pw2c[5],  m2);
            m2 = fmaf(q1.z, pw2c[6],  m2); m2 = fmaf(q1.w, pw2c[7],  m2);
            m2 = fmaf(q2.x, pw2c[8],  m2); m2 = fmaf(q2.y, pw2c[9],  m2);
            m2 = fmaf(q2.z, pw2c[10], m2); m2 = fmaf(q2.w, pw2c[11], m2);
            m2 = fmaf(q3.x, pw2c[12], m2); m2 = fmaf(q3.y, pw2c[13], m2);
            m2 = fmaf(q3.z, pw2c[14], m2); m2 = fmaf(q3.w, pw2c[15], m2);
        }

        // ---- fused final: 64x64 linear (transposed LW, float4) + LN + ReLU + residual ----
        hb[w][5][l] = m2;
        float acc = lb;
        {
            const float4* pr = (const float4*)&hb[w][5][0];
#pragma unroll
            for (int q = 0; q < 16; q++) {
                float4 pv = pr[q];                       // broadcast LDS read
                float4 wv = *(const float4*)(LT + 4 * q);
                acc = fmaf(pv.x, wv.x, acc);
                acc = fmaf(pv.y, wv.y, acc);
                acc = fmaf(pv.z, wv.z, acc);
                acc = fmaf(pv.w, wv.w, acc);
            }
        }
        float s1 = acc, sq = acc * acc;
#pragma unroll
        for (int o = 1; o < 64; o <<= 1) { s1 += __shfl_xor(s1, o); sq += __shfl_xor(sq, o); }
        float mu = s1 * (1.0f / 64.0f);
        float varl = sq * (1.0f / 64.0f) - mu * mu;
        float ln = (acc - mu) * rsqrtf(varl + 1e-5f) * lgm + lbn;
        long idx = (long)n * 64 + l;
        float res = rdin(ax, idx, mode) + fmaxf(ln, 0.f);
        if (mode == 0) ((u16*)outp)[idx] = f2bf(res);
        else           ((float*)outp)[idx] = res;
    }
}

extern "C" void kernel_launch(void* const* d_in, const int* in_sizes, int n_in,
                              void* d_out, int out_size, void* d_ws, size_t ws_size,
                              hipStream_t stream) {
    const void* atom_x   = d_in[0];
    const void* bond_emb = d_in[1];
    const void* edge_w   = d_in[2];
    const void* edge_b   = d_in[3];
    const void* pre_w1   = d_in[4];
    const void* pre_b1   = d_in[5];
    const void* pre_w2   = d_in[6];
    const void* pre_b2   = d_in[7];
    const void* post_w1  = d_in[8];
    const void* post_b1  = d_in[9];
    const void* post_w2  = d_in[10];
    const void* post_b2  = d_in[11];
    const void* lin_w    = d_in[12];
    const void* lin_b    = d_in[13];
    const void* ln_g     = d_in[14];
    const void* ln_b     = d_in[15];
    const int* bond_x    = (const int*)d_in[16];
    const int* aei       = (const int*)d_in[17];

    int E  = in_sizes[16];
    int Nn = in_sizes[0] / 64;
    const int* srcp = aei;
    const int* dstp = aei + E;

    float* wsf = (float*)d_ws;
    int*   wsi = (int*)d_ws;

    size_t o = IB;
    int* modep = wsi + o; o += 16;
    int* cnt   = wsi + o; o += Nn;
    o = (o + 63) & ~(size_t)63;
    int* pk    = wsi + o; o += (size_t)Nn * MAXD;
    float* Yp  = (float*)(wsi + o); o += (size_t)Nn * 64;
    float* XWp = (float*)(wsi + o); o += (size_t)Nn * 64;
    float* XPp = (float*)(wsi + o); o += (size_t)Nn * 64;
    // ws usage ~52 MB

    k_init<<<1600, 256, 0, stream>>>(bond_emb, edge_w, edge_b, pre_w1, pre_b1, pre_w2, pre_b2,
                                     post_w1, post_b1, post_w2, post_b2, lin_w, lin_b, ln_g, ln_b,
                                     atom_x, wsf, Yp, XWp, XPp, cnt, modep, Nn);
    k_scatter<<<(E + 255) / 256, 256, 0, stream>>>(dstp, srcp, bond_x, cnt, pk, wsf, E);
    const int NBLK = 1024;                   // persistent: 4096 waves, ~12 nodes/wave
    k_node<<<NBLK, 256, 0, stream>>>(atom_x, Yp, XWp, XPp, pk, cnt, wsf, d_out,
                                     modep, Nn, NBLK * 4);
}